// Round 6
// baseline (19844.800 us; speedup 1.0000x reference)
//
#include <hip/hip_runtime.h>
#include <math.h>

#define BSZ 512
#define NV  30
#define NT  24
#define SS  768
#define PK  768          // padded K (750 real + 18 zero)
#define PN  1280         // packed cols: sw 0..511, mem 512..1023, sv 1024..1279
#define AROW 772         // LDS state row stride in halves (odd*4 -> conflict-free)
#define NGROUP 16
#define RTHREADS 768     // 12 waves

typedef __attribute__((ext_vector_type(8))) short short8;
typedef __attribute__((ext_vector_type(16))) float f32x16;

__device__ __forceinline__ unsigned short bf16_hi(float f) {
    unsigned u = __float_as_uint(f);
    u += 0x7FFFu + ((u >> 16) & 1u);
    return (unsigned short)(u >> 16);
}
__device__ __forceinline__ float bf16_tof(unsigned short h) {
    return __uint_as_float(((unsigned)h) << 16);
}

// ---------------- prepack: weights -> bf16 hi/lo, [l][n][k] transposed; bias/onehot fp32 packed ----
__global__ void prepack(const float* __restrict__ w1_sw, const float* __restrict__ w1_mem,
                        const float* __restrict__ w1_sv,
                        const float* __restrict__ w_sw,  const float* __restrict__ w_mem,
                        const float* __restrict__ w_sv,
                        const float* __restrict__ b1_sw, const float* __restrict__ b1_mem,
                        const float* __restrict__ b1_sv,
                        const float* __restrict__ b_sw,  const float* __restrict__ b_mem,
                        const float* __restrict__ b_sv,
                        unsigned short* __restrict__ WBh, unsigned short* __restrict__ WBl,
                        float* __restrict__ Biasp, float* __restrict__ OHp)
{
    const long long total = 6LL * PN * PK;
    long long i = (long long)blockIdx.x * blockDim.x + threadIdx.x;
    const long long st = (long long)gridDim.x * blockDim.x;
    for (long long idx = i; idx < total; idx += st) {
        int l = (int)(idx / (PN * PK));
        int rem = (int)(idx - (long long)l * PN * PK);
        int n = rem / PK;
        int k = rem - n * PK;
        float v = 0.f;
        if (k < 750) {
            if (n < 512) {
                if (n < 500) v = (l == 0) ? w1_sw[k * 500 + n]
                                          : w_sw[(size_t)(l - 1) * 750 * 500 + k * 500 + n];
            } else if (n < 1024) {
                int j = n - 512;
                if (j < 500) v = (l == 0) ? w1_mem[k * 500 + j]
                                          : w_mem[(size_t)(l - 1) * 750 * 500 + k * 500 + j];
            } else {
                int j = n - 1024;
                if (j < 250) v = (l == 0) ? w1_sv[k * 250 + j]
                                          : w_sv[(size_t)(l - 1) * 750 * 250 + k * 250 + j];
            }
        }
        unsigned short h = bf16_hi(v);
        WBh[idx] = h;
        WBl[idx] = bf16_hi(v - bf16_tof(h));
    }
    for (long long idx = i; idx < 6 * PN; idx += st) {
        int l = (int)(idx / PN), n = (int)(idx - (long long)l * PN);
        float v = 0.f;
        if (n < 512)       { if (n < 500) v = (l == 0) ? b1_sw[n] : b_sw[(l - 1) * 500 + n]; }
        else if (n < 1024) { int j = n - 512;  if (j < 500) v = (l == 0) ? b1_mem[j] : b_mem[(l - 1) * 500 + j]; }
        else               { int j = n - 1024; if (j < 250) v = (l == 0) ? b1_sv[j]  : b_sv[(l - 1) * 250 + j]; }
        Biasp[idx] = v;
    }
    for (long long idx = i; idx < NV * PN; idx += st) {
        int v = (int)(idx / PN), n = (int)(idx - (long long)v * PN);
        int k = 750 + v;
        float x = 0.f;
        if (n < 512)       { if (n < 500) x = w1_sw[k * 500 + n]; }
        else if (n < 1024) { int j = n - 512;  if (j < 500) x = w1_mem[k * 500 + j]; }
        else               { int j = n - 1024; if (j < 250) x = w1_sv[k * 250 + j]; }
        OHp[idx] = x;
    }
}

// ---------------- persistent per-group recurrent kernel (no cross-block sync) ----------------
// 16 blocks x 768 thr (12 waves). State (32 rows x 768) lives in LDS as bf16 hi/lo planes.
// waves 0..7: 1 sw/mem pair (cols 32w) + 1 sv tile (cols 1024+32w)  -> 3 chains
// waves 8..11: 2 sw/mem pairs (cols 256+(w-8)*64 +{0,32})          -> 4 chains
__launch_bounds__(RTHREADS)
__global__ void recurrent(const int* __restrict__ letters,
                          const unsigned short* __restrict__ WBh,
                          const unsigned short* __restrict__ WBl,
                          const float* __restrict__ Biasp, const float* __restrict__ OHp,
                          float* __restrict__ Sfin)
{
    __shared__ __align__(16) unsigned short Ah[32][AROW];
    __shared__ __align__(16) unsigned short Al[32][AROW];

    const int tid  = threadIdx.x;
    const int lane = tid & 63;
    const int w    = tid >> 6;        // 0..11
    const int ln   = lane & 31;       // col-in-tile / A row m
    const int lk   = lane >> 5;       // k sub-chunk 0/1
    const int m0   = blockIdx.x * 32;

    // zero state planes (k 750..771 stays zero forever)
    for (int i = tid; i < 32 * AROW / 2; i += RTHREADS) {
        ((unsigned*)&Ah[0][0])[i] = 0u;
        ((unsigned*)&Al[0][0])[i] = 0u;
    }
    __syncthreads();

    const bool lowW = (w < 8);
    const int c0 = lowW ? (32 * w) : (256 + (w - 8) * 64);   // first sw tile
    const int c1 = lowW ? (1024 + 32 * w) : (c0 + 32);       // sv tile (low) / second sw tile (high)

    // per-lane half-offsets into WB [n][k]
    const size_t offA = (size_t)(c0 + ln) * PK + lk * 8;          // sw chain 0
    const size_t offAm = (size_t)(512 + c0 + ln) * PK + lk * 8;   // mem chain 0
    const size_t offB = (size_t)(c1 + ln) * PK + lk * 8;          // sv (low) / sw chain 1 (high)
    const size_t offBm = (size_t)(512 + c1 + ln) * PK + lk * 8;   // mem chain 1 (high only)

    for (int t = 0; t < NT; t++) {
        for (int l = 0; l < 6; l++) {
            const unsigned short* __restrict__ wbh = WBh + (size_t)l * PN * PK;
            const unsigned short* __restrict__ wbl = WBl + (size_t)l * PN * PK;

            f32x16 acc0 = {};  // sw chain 0
            f32x16 acc0m = {}; // mem chain 0
            f32x16 acc1 = {};  // sv (low) / sw chain 1 (high)
            f32x16 acc1m = {}; // mem chain 1 (high only)

            for (int ks = 0; ks < 48; ks++) {
                const int kb = ks * 16 + lk * 8;
                // A fragments from LDS (two b64 reads each; odd stride -> conflict-free)
                short8 ahf, alf;
                {
                    unsigned long long v[2];
                    v[0] = *(const unsigned long long*)&Ah[ln][kb];
                    v[1] = *(const unsigned long long*)&Ah[ln][kb + 4];
                    __builtin_memcpy(&ahf, v, 16);
                    v[0] = *(const unsigned long long*)&Al[ln][kb];
                    v[1] = *(const unsigned long long*)&Al[ln][kb + 4];
                    __builtin_memcpy(&alf, v, 16);
                }
                const size_t ko = (size_t)ks * 16;
                short8 bh, bl;
                // chain 0: sw
                __builtin_memcpy(&bh, wbh + offA + ko, 16);
                __builtin_memcpy(&bl, wbl + offA + ko, 16);
                acc0 = __builtin_amdgcn_mfma_f32_32x32x16_bf16(ahf, bh, acc0, 0, 0, 0);
                acc0 = __builtin_amdgcn_mfma_f32_32x32x16_bf16(alf, bh, acc0, 0, 0, 0);
                acc0 = __builtin_amdgcn_mfma_f32_32x32x16_bf16(ahf, bl, acc0, 0, 0, 0);
                // chain 0: mem
                __builtin_memcpy(&bh, wbh + offAm + ko, 16);
                __builtin_memcpy(&bl, wbl + offAm + ko, 16);
                acc0m = __builtin_amdgcn_mfma_f32_32x32x16_bf16(ahf, bh, acc0m, 0, 0, 0);
                acc0m = __builtin_amdgcn_mfma_f32_32x32x16_bf16(alf, bh, acc0m, 0, 0, 0);
                acc0m = __builtin_amdgcn_mfma_f32_32x32x16_bf16(ahf, bl, acc0m, 0, 0, 0);
                // chain 1: sv (low) / sw #2 (high)
                __builtin_memcpy(&bh, wbh + offB + ko, 16);
                __builtin_memcpy(&bl, wbl + offB + ko, 16);
                acc1 = __builtin_amdgcn_mfma_f32_32x32x16_bf16(ahf, bh, acc1, 0, 0, 0);
                acc1 = __builtin_amdgcn_mfma_f32_32x32x16_bf16(alf, bh, acc1, 0, 0, 0);
                acc1 = __builtin_amdgcn_mfma_f32_32x32x16_bf16(ahf, bl, acc1, 0, 0, 0);
                if (!lowW) { // chain 1: mem #2
                    __builtin_memcpy(&bh, wbh + offBm + ko, 16);
                    __builtin_memcpy(&bl, wbl + offBm + ko, 16);
                    acc1m = __builtin_amdgcn_mfma_f32_32x32x16_bf16(ahf, bh, acc1m, 0, 0, 0);
                    acc1m = __builtin_amdgcn_mfma_f32_32x32x16_bf16(alf, bh, acc1m, 0, 0, 0);
                    acc1m = __builtin_amdgcn_mfma_f32_32x32x16_bf16(ahf, bl, acc1m, 0, 0, 0);
                }
            }

            // ---- epilogue compute (reads only) ----
            const float* bp = Biasp + l * PN;
            float mnew0[16], other[16];   // other = xnew (low) or mnew1 (high)
            #pragma unroll
            for (int r = 0; r < 16; r++) {
                const int row = (r & 3) + 8 * (r >> 2) + 4 * lk;
                int lt = -1;
                if (l == 0) lt = letters[(m0 + row) * NT + t];
                // pair 0 m-update (cols c0+ln, always guarded later)
                {
                    float zs = acc0[r] + bp[c0 + ln];
                    float zm = acc0m[r] + bp[512 + c0 + ln];
                    if (lt >= 0) { zs += OHp[lt * PN + c0 + ln]; zm += OHp[lt * PN + 512 + c0 + ln]; }
                    const int mc = 250 + c0 + ln;
                    float mo = bf16_tof(Ah[row][mc]) + bf16_tof(Al[row][mc]);
                    float s = 1.f / (1.f + expf(-zs));
                    mnew0[r] = mo * s + tanhf(zm) * (1.f - s);
                }
                if (lowW) {
                    float zx = acc1[r] + bp[c1 + ln];
                    if (lt >= 0) zx += OHp[lt * PN + c1 + ln];
                    other[r] = tanhf(zx);
                } else {
                    float zs = acc1[r] + bp[c1 + ln];
                    float zm = acc1m[r] + bp[512 + c1 + ln];
                    if (lt >= 0) { zs += OHp[lt * PN + c1 + ln]; zm += OHp[lt * PN + 512 + c1 + ln]; }
                    const int mc = 250 + c1 + ln;
                    float mo = bf16_tof(Ah[row][mc]) + bf16_tof(Al[row][mc]);
                    float s = 1.f / (1.f + expf(-zs));
                    other[r] = mo * s + tanhf(zm) * (1.f - s);
                }
            }

            __syncthreads();   // all reads of old state done

            // ---- state writes ----
            const bool w0ok = (c0 + ln) < 500;
            const bool w1ok = lowW ? ((c1 - 1024 + ln) < 250) : ((c1 + ln) < 500);
            #pragma unroll
            for (int r = 0; r < 16; r++) {
                const int row = (r & 3) + 8 * (r >> 2) + 4 * lk;
                if (w0ok) {
                    const int mc = 250 + c0 + ln;
                    unsigned short h = bf16_hi(mnew0[r]);
                    Ah[row][mc] = h;
                    Al[row][mc] = bf16_hi(mnew0[r] - bf16_tof(h));
                }
                if (w1ok) {
                    const int sc = lowW ? (c1 - 1024 + ln) : (250 + c1 + ln);
                    unsigned short h = bf16_hi(other[r]);
                    Ah[row][sc] = h;
                    Al[row][sc] = bf16_hi(other[r] - bf16_tof(h));
                }
            }
            __syncthreads();   // next gate may read
        }
    }

    // export final state fp32 to global for the head
    for (int idx = tid; idx < 32 * 750; idx += RTHREADS) {
        int r = idx / 750, k = idx - r * 750;
        Sfin[(size_t)(m0 + r) * SS + k] = bf16_tof(Ah[r][k]) + bf16_tof(Al[r][k]);
    }
}

// ---------------- head GEMM: Y = tanh(X @ W + b) ----------------
__launch_bounds__(128)
__global__ void head_gemm(const float* __restrict__ X, int ldx, int K,
                          const float* __restrict__ W, const float* __restrict__ bias,
                          float* __restrict__ Y, int N)
{
    const int tid = threadIdx.x;
    const int m0 = blockIdx.y * 32;
    const int n0 = blockIdx.x * 64;

    __shared__ float As[2][32][36];
    __shared__ float Bs[2][32][68];

    const int tx = tid & 15, ty = tid >> 4;
    const int kl = tid & 31, rl = tid >> 5;
    const int cl = tid & 63, kg = tid >> 6;
    const bool cok = (n0 + cl) < N;

    float acc[4][4] = {{0.f}};
    float ar[8], br[16];

    {
        const float* a = X + (size_t)(m0 + rl) * ldx + kl;
        #pragma unroll
        for (int i = 0; i < 8; i++) ar[i] = a[(size_t)(4 * i) * ldx];
        #pragma unroll
        for (int i = 0; i < 16; i++)
            br[i] = cok ? W[(size_t)(kg + 2 * i) * N + n0 + cl] : 0.f;
        #pragma unroll
        for (int i = 0; i < 8; i++) As[0][kl][rl + 4 * i] = ar[i];
        #pragma unroll
        for (int i = 0; i < 16; i++) Bs[0][kg + 2 * i][cl] = br[i];
    }
    __syncthreads();

    int buf = 0;
    const int NK = (K + 31) / 32;
    #pragma unroll 1
    for (int kt = 0; kt < NK; kt++) {
        const bool more = (kt + 1 < NK);
        if (more) {
            const int k0 = (kt + 1) * 32;
            const bool ka = (k0 + kl) < K;
            const float* a = X + (size_t)(m0 + rl) * ldx + k0 + kl;
            #pragma unroll
            for (int i = 0; i < 8; i++) ar[i] = ka ? a[(size_t)(4 * i) * ldx] : 0.f;
            #pragma unroll
            for (int i = 0; i < 16; i++) {
                const int kk = k0 + kg + 2 * i;
                br[i] = (cok && kk < K) ? W[(size_t)kk * N + n0 + cl] : 0.f;
            }
        }
        #pragma unroll
        for (int kk = 0; kk < 32; kk++) {
            float4 av = *(const float4*)&As[buf][kk][ty * 4];
            float4 bv = *(const float4*)&Bs[buf][kk][tx * 4];
            const float aa[4] = {av.x, av.y, av.z, av.w};
            const float bb[4] = {bv.x, bv.y, bv.z, bv.w};
            #pragma unroll
            for (int i = 0; i < 4; i++)
                #pragma unroll
                for (int j = 0; j < 4; j++)
                    acc[i][j] = fmaf(aa[i], bb[j], acc[i][j]);
        }
        if (more) {
            #pragma unroll
            for (int i = 0; i < 8; i++) As[buf ^ 1][kl][rl + 4 * i] = ar[i];
            #pragma unroll
            for (int i = 0; i < 16; i++) Bs[buf ^ 1][kg + 2 * i][cl] = br[i];
            __syncthreads();
            buf ^= 1;
        }
    }

    #pragma unroll
    for (int i = 0; i < 4; i++) {
        const int b = m0 + ty * 4 + i;
        #pragma unroll
        for (int j = 0; j < 4; j++) {
            const int n = n0 + tx * 4 + j;
            if (n < N) Y[(size_t)b * N + n] = tanhf(acc[i][j] + bias[n]);
        }
    }
}

// ---------------- final: logits (K=100, N=30) + softmax ----------------
__global__ void head_final(const float* __restrict__ Y4, const float* __restrict__ W,
                           const float* __restrict__ bias, float* __restrict__ out)
{
    const int row = blockIdx.x;
    __shared__ float y[100];
    __shared__ float z[NV];
    for (int k = threadIdx.x; k < 100; k += 64) y[k] = Y4[row * 100 + k];
    __syncthreads();
    const int n = threadIdx.x;
    if (n < NV) {
        float acc = bias[n];
        for (int k = 0; k < 100; k++) acc = fmaf(y[k], W[k * NV + n], acc);
        z[n] = acc;
    }
    __syncthreads();
    if (n < NV) {
        float mx = -1e30f;
        for (int i = 0; i < NV; i++) mx = fmaxf(mx, z[i]);
        float sum = 0.f;
        for (int i = 0; i < NV; i++) sum += expf(z[i] - mx);
        out[row * NV + n] = expf(z[n] - mx) / sum;
    }
}

extern "C" void kernel_launch(void* const* d_in, const int* in_sizes, int n_in,
                              void* d_out, int out_size, void* d_ws, size_t ws_size,
                              hipStream_t stream)
{
    const int*   letters = (const int*)  d_in[0];
    const float* w1_sv   = (const float*)d_in[1];
    const float* b1_sv   = (const float*)d_in[2];
    const float* w1_mem  = (const float*)d_in[3];
    const float* b1_mem  = (const float*)d_in[4];
    const float* w1_sw   = (const float*)d_in[5];
    const float* b1_sw   = (const float*)d_in[6];
    const float* w_sv    = (const float*)d_in[7];
    const float* b_sv    = (const float*)d_in[8];
    const float* w_mem   = (const float*)d_in[9];
    const float* b_mem   = (const float*)d_in[10];
    const float* w_sw    = (const float*)d_in[11];
    const float* b_sw    = (const float*)d_in[12];
    const float* wp1 = (const float*)d_in[13]; const float* bp1 = (const float*)d_in[14];
    const float* wp2 = (const float*)d_in[15]; const float* bp2 = (const float*)d_in[16];
    const float* wp3 = (const float*)d_in[17]; const float* bp3 = (const float*)d_in[18];
    const float* wp4 = (const float*)d_in[19]; const float* bp4 = (const float*)d_in[20];
    const float* wp5 = (const float*)d_in[21]; const float* bp5 = (const float*)d_in[22];

    float* S0 = (float*)d_ws;                                   // 512*768 fp32
    unsigned short* WBh = (unsigned short*)(S0 + (size_t)BSZ * SS);
    unsigned short* WBl = WBh + (size_t)6 * PN * PK;
    float* Biasp = (float*)(WBl + (size_t)6 * PN * PK);         // 6*1280
    float* OHp   = Biasp + 6 * PN;                              // 30*1280
    float* Y1 = OHp + NV * PN;
    float* Y2 = Y1 + (size_t)BSZ * 450;
    float* Y3 = Y2 + (size_t)BSZ * 300;
    float* Y4 = Y3 + (size_t)BSZ * 200;

    prepack<<<1024, 256, 0, stream>>>(w1_sw, w1_mem, w1_sv, w_sw, w_mem, w_sv,
                                      b1_sw, b1_mem, b1_sv, b_sw, b_mem, b_sv,
                                      WBh, WBl, Biasp, OHp);
    recurrent<<<NGROUP, RTHREADS, 0, stream>>>(letters, WBh, WBl, Biasp, OHp, S0);

    head_gemm<<<dim3(8, 16), 128, 0, stream>>>(S0, SS, 750, wp1, bp1, Y1, 450);
    head_gemm<<<dim3(5, 16), 128, 0, stream>>>(Y1, 450, 450, wp2, bp2, Y2, 300);
    head_gemm<<<dim3(4, 16), 128, 0, stream>>>(Y2, 300, 300, wp3, bp3, Y3, 200);
    head_gemm<<<dim3(2, 16), 128, 0, stream>>>(Y3, 200, 200, wp4, bp4, Y4, 100);
    head_final<<<BSZ, 64, 0, stream>>>(Y4, wp5, bp5, (float*)d_out);
}

// Round 7
// 7439.003 us; speedup vs baseline: 2.6677x; 2.6677x over previous
//
#include <hip/hip_runtime.h>
#include <math.h>

#define BSZ 512
#define NV  30
#define NT  24
#define SS  768
#define PK  768          // padded K (750 real + 18 zero)
#define PN  1280         // packed cols: sw 0..511, mem 512..1023, sv 1024..1279
#define AROW 772         // LDS state row stride in halves
#define NGROUP 16
#define NSLICE 8
#define RTHREADS 320     // 5 waves: w0,w1=sw tiles, w2,w3=mem tiles, w4=sv tile
#define ZROW 1280
#define ZGRP (32 * ZROW)
#define ZPAR (NGROUP * ZGRP)

typedef __attribute__((ext_vector_type(8))) short short8;
typedef __attribute__((ext_vector_type(16))) float f32x16;

__device__ __forceinline__ unsigned short bf16_hi(float f) {
    unsigned u = __float_as_uint(f);
    u += 0x7FFFu + ((u >> 16) & 1u);
    return (unsigned short)(u >> 16);
}
__device__ __forceinline__ float bf16_tof(unsigned short h) {
    return __uint_as_float(((unsigned)h) << 16);
}
__device__ __forceinline__ unsigned long long ldz2(const float* p) {
    return __hip_atomic_load((const unsigned long long*)p, __ATOMIC_RELAXED, __HIP_MEMORY_SCOPE_AGENT);
}
__device__ __forceinline__ void stz(float* p, float v) {
    __hip_atomic_store(p, v, __ATOMIC_RELAXED, __HIP_MEMORY_SCOPE_AGENT);
}

// ---------------- init: zero barrier counters ----------------
__global__ void init_kernel(unsigned* ctrs) {
    if (threadIdx.x < NGROUP * 16) ctrs[threadIdx.x] = 0u;
}

// ---------------- prepack (same as R6, validated): WB [l][n][k] bf16 hi/lo ----------------
__global__ void prepack(const float* __restrict__ w1_sw, const float* __restrict__ w1_mem,
                        const float* __restrict__ w1_sv,
                        const float* __restrict__ w_sw,  const float* __restrict__ w_mem,
                        const float* __restrict__ w_sv,
                        const float* __restrict__ b1_sw, const float* __restrict__ b1_mem,
                        const float* __restrict__ b1_sv,
                        const float* __restrict__ b_sw,  const float* __restrict__ b_mem,
                        const float* __restrict__ b_sv,
                        unsigned short* __restrict__ WBh, unsigned short* __restrict__ WBl,
                        float* __restrict__ Biasp, float* __restrict__ OHp)
{
    const long long total = 6LL * PN * PK;
    long long i = (long long)blockIdx.x * blockDim.x + threadIdx.x;
    const long long st = (long long)gridDim.x * blockDim.x;
    for (long long idx = i; idx < total; idx += st) {
        int l = (int)(idx / (PN * PK));
        int rem = (int)(idx - (long long)l * PN * PK);
        int n = rem / PK;
        int k = rem - n * PK;
        float v = 0.f;
        if (k < 750) {
            if (n < 512) {
                if (n < 500) v = (l == 0) ? w1_sw[k * 500 + n]
                                          : w_sw[(size_t)(l - 1) * 750 * 500 + k * 500 + n];
            } else if (n < 1024) {
                int j = n - 512;
                if (j < 500) v = (l == 0) ? w1_mem[k * 500 + j]
                                          : w_mem[(size_t)(l - 1) * 750 * 500 + k * 500 + j];
            } else {
                int j = n - 1024;
                if (j < 250) v = (l == 0) ? w1_sv[k * 250 + j]
                                          : w_sv[(size_t)(l - 1) * 750 * 250 + k * 250 + j];
            }
        }
        unsigned short h = bf16_hi(v);
        WBh[idx] = h;
        WBl[idx] = bf16_hi(v - bf16_tof(h));
    }
    for (long long idx = i; idx < 6 * PN; idx += st) {
        int l = (int)(idx / PN), n = (int)(idx - (long long)l * PN);
        float v = 0.f;
        if (n < 512)       { if (n < 500) v = (l == 0) ? b1_sw[n] : b_sw[(l - 1) * 500 + n]; }
        else if (n < 1024) { int j = n - 512;  if (j < 500) v = (l == 0) ? b1_mem[j] : b_mem[(l - 1) * 500 + j]; }
        else               { int j = n - 1024; if (j < 250) v = (l == 0) ? b1_sv[j]  : b_sv[(l - 1) * 250 + j]; }
        Biasp[idx] = v;
    }
    for (long long idx = i; idx < NV * PN; idx += st) {
        int v = (int)(idx / PN), n = (int)(idx - (long long)v * PN);
        int k = 750 + v;
        float x = 0.f;
        if (n < 512)       { if (n < 500) x = w1_sw[k * 500 + n]; }
        else if (n < 1024) { int j = n - 512;  if (j < 500) x = w1_mem[k * 500 + j]; }
        else               { int j = n - 1024; if (j < 250) x = w1_sv[k * 250 + j]; }
        OHp[idx] = x;
    }
}

// one GEMM K-step (4-stage B prefetch); BH/BL are this stage's registers
#define GSTEP(I, BH, BL) {                                                      \
    const int ks = 4 * j + (I);                                                 \
    const int kb = ks * 16 + lk * 8;                                            \
    unsigned long long va[2], vb[2];                                            \
    va[0] = *(const unsigned long long*)&Ah[ln][kb];                            \
    va[1] = *(const unsigned long long*)&Ah[ln][kb + 4];                        \
    vb[0] = *(const unsigned long long*)&Al[ln][kb];                            \
    vb[1] = *(const unsigned long long*)&Al[ln][kb + 4];                        \
    short8 ahf, alf;                                                            \
    __builtin_memcpy(&ahf, va, 16);                                             \
    __builtin_memcpy(&alf, vb, 16);                                             \
    acc = __builtin_amdgcn_mfma_f32_32x32x16_bf16(ahf, BH, acc, 0, 0, 0);       \
    acc = __builtin_amdgcn_mfma_f32_32x32x16_bf16(alf, BH, acc, 0, 0, 0);       \
    acc = __builtin_amdgcn_mfma_f32_32x32x16_bf16(ahf, BL, acc, 0, 0, 0);       \
    if (j < 11) {                                                               \
        __builtin_memcpy(&BH, wbh + offB + (size_t)(ks + 4) * 16, 16);          \
        __builtin_memcpy(&BL, wbl + offB + (size_t)(ks + 4) * 16, 16);          \
    }                                                                           \
}

// ---------------- persistent recurrent kernel: 128 blocks = 16 groups x 8 slices ----------------
__launch_bounds__(RTHREADS)
__global__ void recurrent(const int* __restrict__ letters,
                          const unsigned short* __restrict__ WBh,
                          const unsigned short* __restrict__ WBl,
                          const float* __restrict__ Biasp, const float* __restrict__ OHp,
                          float* __restrict__ zbuf, unsigned* __restrict__ ctrs,
                          float* __restrict__ Sfin)
{
    __shared__ __align__(16) unsigned short Ah[32][AROW];
    __shared__ __align__(16) unsigned short Al[32][AROW];

    const int tid  = threadIdx.x;
    const int lane = tid & 63;
    const int w    = tid >> 6;        // 0..4
    const int ln   = lane & 31;
    const int lk   = lane >> 5;
    const int gid  = blockIdx.x;
    const int g    = gid >> 3;        // group (32 batch rows)
    const int s    = gid & 7;         // col-slice -> XCD s (heuristic)
    const int m0   = g * 32;
    unsigned* ctr  = ctrs + g * 16;

    // wave's packed output column base
    const int cw = (w < 2) ? (64 * s + 32 * w)
                 : (w < 4) ? (512 + 64 * s + 32 * (w - 2))
                           : (1024 + 32 * s);
    const size_t offB = (size_t)(cw + ln) * PK + lk * 8;

    // zero state planes (cols 750..771 stay zero forever)
    for (int i = tid; i < 32 * AROW / 2; i += RTHREADS) {
        ((unsigned*)&Ah[0][0])[i] = 0u;
        ((unsigned*)&Al[0][0])[i] = 0u;
    }
    __syncthreads();

    for (int t = 0; t < NT; t++) {
        for (int l = 0; l < 6; l++) {
            const int gi = t * 6 + l;
            const unsigned short* __restrict__ wbh = WBh + (size_t)l * PN * PK;
            const unsigned short* __restrict__ wbl = WBl + (size_t)l * PN * PK;
            float* __restrict__ zg = zbuf + (size_t)(gi & 1) * ZPAR + (size_t)g * ZGRP;

            // ---- GEMM: acc = S[32 x 768] @ W[:, cw..cw+32), 3-chain hi/lo ----
            f32x16 acc = {};
            short8 b0h, b0l, b1h, b1l, b2h, b2l, b3h, b3l;
            __builtin_memcpy(&b0h, wbh + offB +  0, 16);
            __builtin_memcpy(&b0l, wbl + offB +  0, 16);
            __builtin_memcpy(&b1h, wbh + offB + 16, 16);
            __builtin_memcpy(&b1l, wbl + offB + 16, 16);
            __builtin_memcpy(&b2h, wbh + offB + 32, 16);
            __builtin_memcpy(&b2l, wbl + offB + 32, 16);
            __builtin_memcpy(&b3h, wbh + offB + 48, 16);
            __builtin_memcpy(&b3l, wbl + offB + 48, 16);
            #pragma unroll 1
            for (int j = 0; j < 12; j++) {
                GSTEP(0, b0h, b0l)
                GSTEP(1, b1h, b1l)
                GSTEP(2, b2h, b2l)
                GSTEP(3, b3h, b3l)
            }

            // ---- publish z slice (agent stores -> LLC), row-major [row][1280] ----
            #pragma unroll
            for (int r = 0; r < 16; r++) {
                const int row = (r & 3) + 8 * (r >> 2) + 4 * lk;
                stz(zg + (size_t)row * ZROW + cw + ln, acc[r]);
            }

            // ---- group barrier: all 8 slices' z visible ----
            __builtin_amdgcn_s_waitcnt(0);   // each wave drains its own stores
            __syncthreads();
            if (tid == 0) {
                __hip_atomic_fetch_add(ctr, 1u, __ATOMIC_RELAXED, __HIP_MEMORY_SCOPE_AGENT);
                const unsigned target = 8u * (unsigned)(gi + 1);
                while (__hip_atomic_load(ctr, __ATOMIC_RELAXED, __HIP_MEMORY_SCOPE_AGENT) < target)
                    __builtin_amdgcn_s_sleep(1);
            }
            __syncthreads();

            // ---- replicated epilogue: gather z, update full LDS state ----
            const float* bp = Biasp + l * PN;
            #pragma unroll 4
            for (int it = 0; it < 38; it++) {
                const int idx = tid + RTHREADS * it;
                if (idx < 12000) {  // 32 rows x 375 col-pairs
                    const int row = idx / 375;
                    const int p   = idx - row * 375;
                    const float* zr = zg + (size_t)row * ZROW;
                    const int lt = (l == 0) ? letters[(m0 + row) * NT + t] : -1;
                    const float* ohr = (lt >= 0) ? (OHp + lt * PN) : nullptr;
                    if (p < 250) {           // m-pair: state cols 250+c2, 251+c2
                        const int c2 = 2 * p;
                        unsigned long long u0 = ldz2(zr + c2);
                        unsigned long long u1 = ldz2(zr + 512 + c2);
                        float zs0 = __uint_as_float((unsigned)u0) + bp[c2];
                        float zs1 = __uint_as_float((unsigned)(u0 >> 32)) + bp[c2 + 1];
                        float zm0 = __uint_as_float((unsigned)u1) + bp[512 + c2];
                        float zm1 = __uint_as_float((unsigned)(u1 >> 32)) + bp[512 + c2 + 1];
                        if (ohr) { zs0 += ohr[c2]; zs1 += ohr[c2 + 1]; zm0 += ohr[512 + c2]; zm1 += ohr[512 + c2 + 1]; }
                        const int sc = 250 + c2;
                        float mo0 = bf16_tof(Ah[row][sc])     + bf16_tof(Al[row][sc]);
                        float mo1 = bf16_tof(Ah[row][sc + 1]) + bf16_tof(Al[row][sc + 1]);
                        float s0 = 1.f / (1.f + expf(-zs0));
                        float s1 = 1.f / (1.f + expf(-zs1));
                        float mn0 = mo0 * s0 + tanhf(zm0) * (1.f - s0);
                        float mn1 = mo1 * s1 + tanhf(zm1) * (1.f - s1);
                        unsigned short h0 = bf16_hi(mn0), h1 = bf16_hi(mn1);
                        *(unsigned*)&Ah[row][sc] = (unsigned)h0 | ((unsigned)h1 << 16);
                        unsigned short l0 = bf16_hi(mn0 - bf16_tof(h0));
                        unsigned short l1 = bf16_hi(mn1 - bf16_tof(h1));
                        *(unsigned*)&Al[row][sc] = (unsigned)l0 | ((unsigned)l1 << 16);
                    } else {                 // x-pair: state cols c2, c2+1
                        const int c2 = 2 * (p - 250);
                        unsigned long long u = ldz2(zr + 1024 + c2);
                        float zx0 = __uint_as_float((unsigned)u) + bp[1024 + c2];
                        float zx1 = __uint_as_float((unsigned)(u >> 32)) + bp[1024 + c2 + 1];
                        if (ohr) { zx0 += ohr[1024 + c2]; zx1 += ohr[1024 + c2 + 1]; }
                        float x0 = tanhf(zx0), x1 = tanhf(zx1);
                        unsigned short h0 = bf16_hi(x0), h1 = bf16_hi(x1);
                        *(unsigned*)&Ah[row][c2] = (unsigned)h0 | ((unsigned)h1 << 16);
                        unsigned short l0 = bf16_hi(x0 - bf16_tof(h0));
                        unsigned short l1 = bf16_hi(x1 - bf16_tof(h1));
                        *(unsigned*)&Al[row][c2] = (unsigned)l0 | ((unsigned)l1 << 16);
                    }
                }
            }
            __syncthreads();
        }
    }

    // slice-0 blocks export final state (fp32) for the head
    if (s == 0) {
        for (int idx = tid; idx < 32 * 750; idx += RTHREADS) {
            int r = idx / 750, k = idx - r * 750;
            Sfin[(size_t)(m0 + r) * SS + k] = bf16_tof(Ah[r][k]) + bf16_tof(Al[r][k]);
        }
    }
}

// ---------------- head GEMM: Y = tanh(X @ W + b) ----------------
__launch_bounds__(128)
__global__ void head_gemm(const float* __restrict__ X, int ldx, int K,
                          const float* __restrict__ W, const float* __restrict__ bias,
                          float* __restrict__ Y, int N)
{
    const int tid = threadIdx.x;
    const int m0 = blockIdx.y * 32;
    const int n0 = blockIdx.x * 64;

    __shared__ float As[2][32][36];
    __shared__ float Bs[2][32][68];

    const int tx = tid & 15, ty = tid >> 4;
    const int kl = tid & 31, rl = tid >> 5;
    const int cl = tid & 63, kg = tid >> 6;
    const bool cok = (n0 + cl) < N;

    float acc[4][4] = {{0.f}};
    float ar[8], br[16];

    {
        const float* a = X + (size_t)(m0 + rl) * ldx + kl;
        #pragma unroll
        for (int i = 0; i < 8; i++) ar[i] = a[(size_t)(4 * i) * ldx];
        #pragma unroll
        for (int i = 0; i < 16; i++)
            br[i] = cok ? W[(size_t)(kg + 2 * i) * N + n0 + cl] : 0.f;
        #pragma unroll
        for (int i = 0; i < 8; i++) As[0][kl][rl + 4 * i] = ar[i];
        #pragma unroll
        for (int i = 0; i < 16; i++) Bs[0][kg + 2 * i][cl] = br[i];
    }
    __syncthreads();

    int buf = 0;
    const int NK = (K + 31) / 32;
    #pragma unroll 1
    for (int kt = 0; kt < NK; kt++) {
        const bool more = (kt + 1 < NK);
        if (more) {
            const int k0 = (kt + 1) * 32;
            const bool ka = (k0 + kl) < K;
            const float* a = X + (size_t)(m0 + rl) * ldx + k0 + kl;
            #pragma unroll
            for (int i = 0; i < 8; i++) ar[i] = ka ? a[(size_t)(4 * i) * ldx] : 0.f;
            #pragma unroll
            for (int i = 0; i < 16; i++) {
                const int kk = k0 + kg + 2 * i;
                br[i] = (cok && kk < K) ? W[(size_t)kk * N + n0 + cl] : 0.f;
            }
        }
        #pragma unroll
        for (int kk = 0; kk < 32; kk++) {
            float4 av = *(const float4*)&As[buf][kk][ty * 4];
            float4 bv = *(const float4*)&Bs[buf][kk][tx * 4];
            const float aa[4] = {av.x, av.y, av.z, av.w};
            const float bb[4] = {bv.x, bv.y, bv.z, bv.w};
            #pragma unroll
            for (int i = 0; i < 4; i++)
                #pragma unroll
                for (int j = 0; j < 4; j++)
                    acc[i][j] = fmaf(aa[i], bb[j], acc[i][j]);
        }
        if (more) {
            #pragma unroll
            for (int i = 0; i < 8; i++) As[buf ^ 1][kl][rl + 4 * i] = ar[i];
            #pragma unroll
            for (int i = 0; i < 16; i++) Bs[buf ^ 1][kg + 2 * i][cl] = br[i];
            __syncthreads();
            buf ^= 1;
        }
    }

    #pragma unroll
    for (int i = 0; i < 4; i++) {
        const int b = m0 + ty * 4 + i;
        #pragma unroll
        for (int j = 0; j < 4; j++) {
            const int n = n0 + tx * 4 + j;
            if (n < N) Y[(size_t)b * N + n] = tanhf(acc[i][j] + bias[n]);
        }
    }
}

// ---------------- final: logits (K=100, N=30) + softmax ----------------
__global__ void head_final(const float* __restrict__ Y4, const float* __restrict__ W,
                           const float* __restrict__ bias, float* __restrict__ out)
{
    const int row = blockIdx.x;
    __shared__ float y[100];
    __shared__ float z[NV];
    for (int k = threadIdx.x; k < 100; k += 64) y[k] = Y4[row * 100 + k];
    __syncthreads();
    const int n = threadIdx.x;
    if (n < NV) {
        float acc = bias[n];
        for (int k = 0; k < 100; k++) acc = fmaf(y[k], W[k * NV + n], acc);
        z[n] = acc;
    }
    __syncthreads();
    if (n < NV) {
        float mx = -1e30f;
        for (int i = 0; i < NV; i++) mx = fmaxf(mx, z[i]);
        float sum = 0.f;
        for (int i = 0; i < NV; i++) sum += expf(z[i] - mx);
        out[row * NV + n] = expf(z[n] - mx) / sum;
    }
}

extern "C" void kernel_launch(void* const* d_in, const int* in_sizes, int n_in,
                              void* d_out, int out_size, void* d_ws, size_t ws_size,
                              hipStream_t stream)
{
    const int*   letters = (const int*)  d_in[0];
    const float* w1_sv   = (const float*)d_in[1];
    const float* b1_sv   = (const float*)d_in[2];
    const float* w1_mem  = (const float*)d_in[3];
    const float* b1_mem  = (const float*)d_in[4];
    const float* w1_sw   = (const float*)d_in[5];
    const float* b1_sw   = (const float*)d_in[6];
    const float* w_sv    = (const float*)d_in[7];
    const float* b_sv    = (const float*)d_in[8];
    const float* w_mem   = (const float*)d_in[9];
    const float* b_mem   = (const float*)d_in[10];
    const float* w_sw    = (const float*)d_in[11];
    const float* b_sw    = (const float*)d_in[12];
    const float* wp1 = (const float*)d_in[13]; const float* bp1 = (const float*)d_in[14];
    const float* wp2 = (const float*)d_in[15]; const float* bp2 = (const float*)d_in[16];
    const float* wp3 = (const float*)d_in[17]; const float* bp3 = (const float*)d_in[18];
    const float* wp4 = (const float*)d_in[19]; const float* bp4 = (const float*)d_in[20];
    const float* wp5 = (const float*)d_in[21]; const float* bp5 = (const float*)d_in[22];

    float* Sfin = (float*)d_ws;                                  // 512*768 fp32
    unsigned short* WBh = (unsigned short*)(Sfin + (size_t)BSZ * SS);
    unsigned short* WBl = WBh + (size_t)6 * PN * PK;
    float* Biasp = (float*)(WBl + (size_t)6 * PN * PK);          // 6*1280
    float* OHp   = Biasp + 6 * PN;                               // 30*1280
    float* Zb    = OHp + NV * PN;                                // 2 * ZPAR
    unsigned* ctrs = (unsigned*)(Zb + 2 * (size_t)ZPAR);         // 256 u32
    float* Y1 = (float*)(ctrs + 256);
    float* Y2 = Y1 + (size_t)BSZ * 450;
    float* Y3 = Y2 + (size_t)BSZ * 300;
    float* Y4 = Y3 + (size_t)BSZ * 200;

    init_kernel<<<1, 256, 0, stream>>>(ctrs);
    prepack<<<1024, 256, 0, stream>>>(w1_sw, w1_mem, w1_sv, w_sw, w_mem, w_sv,
                                      b1_sw, b1_mem, b1_sv, b_sw, b_mem, b_sv,
                                      WBh, WBl, Biasp, OHp);
    recurrent<<<NGROUP * NSLICE, RTHREADS, 0, stream>>>(letters, WBh, WBl, Biasp, OHp,
                                                        Zb, ctrs, Sfin);

    head_gemm<<<dim3(8, 16), 128, 0, stream>>>(Sfin, SS, 750, wp1, bp1, Y1, 450);
    head_gemm<<<dim3(5, 16), 128, 0, stream>>>(Y1, 450, 450, wp2, bp2, Y2, 300);
    head_gemm<<<dim3(4, 16), 128, 0, stream>>>(Y2, 300, 300, wp3, bp3, Y3, 200);
    head_gemm<<<dim3(2, 16), 128, 0, stream>>>(Y3, 200, 200, wp4, bp4, Y4, 100);
    head_final<<<BSZ, 64, 0, stream>>>(Y4, wp5, bp5, (float*)d_out);
}